// Round 8
// baseline (267.907 us; speedup 1.0000x reference)
//
#include <hip/hip_runtime.h>
#include <hip/hip_bf16.h>
#include <stdint.h>

#define B_ 16
#define N_ 2500

typedef unsigned short u16;
typedef __attribute__((ext_vector_type(8))) short bf16x8;
typedef __attribute__((ext_vector_type(4))) float f32x4;

// cold-path manual RNE (k_pack only)
__device__ __forceinline__ u16 f2bf_sw(float f) {
  unsigned u = __float_as_uint(f);
  return (u16)((u + 0x7fffu + ((u >> 16) & 1u)) >> 16);
}
// hot-path HW convert (single)
__device__ __forceinline__ u16 f2bf(float f) {
  __hip_bfloat16 h = __float2bfloat16(f);
  return __builtin_bit_cast(u16, h);
}
// hot-path HW convert (pair) — two scalar casts; compiler packs
__device__ __forceinline__ unsigned f2bf2(float lo, float hi) {
  return (unsigned)f2bf(lo) | ((unsigned)f2bf(hi) << 16);
}
__device__ __forceinline__ float sigm(float x) {
  return __builtin_amdgcn_rcpf(1.f + __expf(-x));
}

// Blob layout (u32 units): th 0..6144, eW 6144..7680, gW 7680..8704,
// w1 8704..9216, w2 9216..9728, nW2 frags 9728..11776, params(f32) 11776..12448.
#define BLOB_U32 12448

// ---------- kernel P: pack all weights into fragment blob ----------
__global__ __launch_bounds__(256) void k_pack(
    const float* __restrict__ theta, const float* __restrict__ edgeW,
    const float* __restrict__ gateW, const float* __restrict__ wW1,
    const float* __restrict__ wW2, const float* __restrict__ nW2,
    const float* __restrict__ theta_b, const float* __restrict__ gate_b,
    const float* __restrict__ edge_b,
    const float* __restrict__ ws1, const float* __restrict__ wb1, const float* __restrict__ wsh1,
    const float* __restrict__ ns2, const float* __restrict__ nb2, const float* __restrict__ nsh2,
    const float* __restrict__ ws2, const float* __restrict__ wb2, const float* __restrict__ wsh2,
    unsigned* __restrict__ blob) {
  const int tid = threadIdx.x;
  for (int q = tid; q < 6144; q += 256) {  // theta frags: f = t*8 + mt*2 + h
    int f = q >> 8, lane = (q >> 2) & 63, jp = q & 3;
    int t = f >> 3, mt = (f >> 1) & 3, h = f & 1;
    int el = lane & 15, kg = lane >> 4;
    const float* s = theta + ((size_t)t * 64 + mt * 16 + el) * 64 + h * 32 + kg * 8 + jp * 2;
    blob[q] = (unsigned)f2bf_sw(s[0]) | ((unsigned)f2bf_sw(s[1]) << 16);
  }
  for (int q = tid; q < 1536; q += 256) {  // edgeW frags: f = mt*3 + s
    int f = q >> 8, lane = (q >> 2) & 63, jp = q & 3;
    int mt = f / 3, ss = f - mt * 3;
    int el = lane & 15, kg = lane >> 4;
    const float* s = edgeW + ((size_t)mt * 16 + el) * 96 + ss * 32 + kg * 8 + jp * 2;
    blob[6144 + q] = (unsigned)f2bf_sw(s[0]) | ((unsigned)f2bf_sw(s[1]) << 16);
  }
  for (int q = tid; q < 1024; q += 256) {  // gateW frags: f = mt
    int f = q >> 8, lane = (q >> 2) & 63, jp = q & 3;
    int el = lane & 15, kg = lane >> 4;
    const float* s = gateW + ((size_t)f * 16 + el) * 32 + kg * 8 + jp * 2;
    blob[7680 + q] = (unsigned)f2bf_sw(s[0]) | ((unsigned)f2bf_sw(s[1]) << 16);
  }
  for (int q = tid; q < 512; q += 256) {  // wW1/wW2 frags: f = mt
    int f = q >> 8, lane = (q >> 2) & 63, jp = q & 3;
    int el = lane & 15, kg = lane >> 4;
    const float* s1 = wW1 + (size_t)(f * 16 + el) * 32 + kg * 8 + jp * 2;
    const float* s2 = wW2 + (size_t)(f * 16 + el) * 32 + kg * 8 + jp * 2;
    blob[8704 + q] = (unsigned)f2bf_sw(s1[0]) | ((unsigned)f2bf_sw(s1[1]) << 16);
    blob[9216 + q] = (unsigned)f2bf_sw(s2[0]) | ((unsigned)f2bf_sw(s2[1]) << 16);
  }
  for (int q = tid; q < 2048; q += 256) {  // nW2 frags: f = mt*2 + h
    int f = q >> 8, lane = (q >> 2) & 63, jp = q & 3;
    int mt = f >> 1, h = f & 1;
    int el = lane & 15, kg = lane >> 4;
    const float* s = nW2 + (size_t)(mt * 16 + el) * 64 + h * 32 + kg * 8 + jp * 2;
    blob[9728 + q] = (unsigned)f2bf_sw(s[0]) | ((unsigned)f2bf_sw(s[1]) << 16);
  }
  float* bf = (float*)blob;
  for (int i = tid; i < 672; i += 256) {
    float v;
    if (i < 192)      v = theta_b[i];
    else if (i < 256) v = gate_b[i - 192];
    else if (i < 320) v = ns2[i - 256];
    else if (i < 384) v = nb2[i - 320];
    else if (i < 448) v = nsh2[i - 384];
    else if (i < 480) v = edge_b[i - 448];
    else if (i < 512) v = ws1[i - 480];
    else if (i < 544) v = wb1[i - 512];
    else if (i < 576) v = wsh1[i - 544];
    else if (i < 608) v = ws2[i - 576];
    else if (i < 640) v = wb2[i - 608];
    else              v = wsh2[i - 640];
    bf[11776 + i] = v;
  }
}

// ---------- kernel A: nf1 = relu(bn(nW1 @ node)) -> bf16 [b*N+n][64], MFMA ----------
__global__ __launch_bounds__(256) void k_nf1(
    const float* __restrict__ node, const float* __restrict__ W,
    const float* __restrict__ bia, const float* __restrict__ sc,
    const float* __restrict__ sh, u16* __restrict__ nf1b) {
  __shared__ __align__(16) u16 W_p[8 * 64 * 8];
  __shared__ float bia_s[64], sc_s[64], sh_s[64];
  const int tid = threadIdx.x;
  for (int q = tid; q < 2048; q += 256) {
    int f = q >> 8, lane = (q >> 2) & 63, jp = q & 3;
    int mt = f >> 1, h = f & 1;
    int fel = lane & 15, fkg = lane >> 4;
    const float* src = W + (size_t)(mt * 16 + fel) * 64 + h * 32 + fkg * 8 + jp * 2;
    ((unsigned*)W_p)[q] = f2bf2(src[0], src[1]);
  }
  if (tid < 64) { bia_s[tid] = bia[tid]; sc_s[tid] = sc[tid]; sh_s[tid] = sh[tid]; }
  __syncthreads();

  const int l = tid & 63, wv = tid >> 6;
  const int el = l & 15, kg = l >> 4;
  const int bn = blockIdx.x * 64 + wv * 16 + el;
  const int b = bn / N_;
  const int n = bn - b * N_;

  union UF { bf16x8 v; uint4 q; } xb0, xb1;
  const float* xp0 = node + (size_t)(b * 64 + kg * 8) * N_ + n;
  const float* xp1 = node + (size_t)(b * 64 + 32 + kg * 8) * N_ + n;
  {
    float a0[8], a1[8];
#pragma unroll
    for (int j = 0; j < 8; ++j) { a0[j] = xp0[(size_t)j * N_]; a1[j] = xp1[(size_t)j * N_]; }
    xb0.q.x = f2bf2(a0[0], a0[1]); xb0.q.y = f2bf2(a0[2], a0[3]);
    xb0.q.z = f2bf2(a0[4], a0[5]); xb0.q.w = f2bf2(a0[6], a0[7]);
    xb1.q.x = f2bf2(a1[0], a1[1]); xb1.q.y = f2bf2(a1[2], a1[3]);
    xb1.q.z = f2bf2(a1[4], a1[5]); xb1.q.w = f2bf2(a1[6], a1[7]);
  }
  const f32x4 z4 = {0.f, 0.f, 0.f, 0.f};
#pragma unroll
  for (int mt = 0; mt < 4; ++mt) {
    bf16x8 a0 = *(const bf16x8*)&W_p[((mt * 2 + 0) * 64 + l) * 8];
    bf16x8 a1 = *(const bf16x8*)&W_p[((mt * 2 + 1) * 64 + l) * 8];
    f32x4 acc = __builtin_amdgcn_mfma_f32_16x16x32_bf16(a0, xb0.v, z4, 0, 0, 0);
    acc = __builtin_amdgcn_mfma_f32_16x16x32_bf16(a1, xb1.v, acc, 0, 0, 0);
    int ob = mt * 16 + kg * 4;
    float4 s4 = *(const float4*)&sc_s[ob];
    float4 b4 = *(const float4*)&bia_s[ob];
    float4 h4 = *(const float4*)&sh_s[ob];
    uint2 d;
    d.x = f2bf2(fmaxf(fmaf(s4.x, acc[0] + b4.x, h4.x), 0.f),
                fmaxf(fmaf(s4.y, acc[1] + b4.y, h4.y), 0.f));
    d.y = f2bf2(fmaxf(fmaf(s4.z, acc[2] + b4.z, h4.z), 0.f),
                fmaxf(fmaf(s4.w, acc[3] + b4.w, h4.w), 0.f));
    *(uint2*)&nf1b[(size_t)bn * 64 + ob] = d;
  }
}

// ---------- kernel B: fused MFMA message passing ----------
// 1024 threads = 16 waves in ONE workgroup (forced co-residency);
// 64-node window; wave wv handles nodes wv, wv+16, wv+32, wv+48. grid 625.
__global__ __launch_bounds__(1024, 4) void k_fused(
    const float* __restrict__ node, const float* __restrict__ wfeat,
    const int* __restrict__ etype, const int* __restrict__ nn_idx,
    const u16* __restrict__ nf1b, const unsigned* __restrict__ blob,
    float* __restrict__ out_nf, float* __restrict__ out_wf) {

  __shared__ __align__(16) unsigned char sm[BLOB_U32 * 4];  // 49792 B
  __shared__ __align__(16) u16 nout_bf[64 * 64];            // 8192 B, swizzled
  __shared__ __align__(16) u16 Rx[16][512];                 // 16384 B

  const int tid = threadIdx.x;
  for (int i = tid; i < BLOB_U32 / 4; i += 1024)
    ((uint4*)sm)[i] = ((const uint4*)blob)[i];

  const u16* th_p   = (const u16*)sm;
  const u16* eW_p   = (const u16*)(sm + 24576);
  const u16* gW_p   = (const u16*)(sm + 30720);
  const u16* w1_p   = (const u16*)(sm + 34816);
  const u16* w2_p   = (const u16*)(sm + 36864);
  const u16* nW2f_p = (const u16*)(sm + 38912);
  const float* par = (const float*)(sm + 47104);
  const float* tb_s  = par;
  const float* gb_s  = par + 192;
  const float* ns2_s = par + 256;
  const float* nb2_s = par + 320;
  const float* nsh2_s= par + 384;
  const float* eb_s  = par + 448;
  const float* ws1_s = par + 480;
  const float* wb1_s = par + 512;
  const float* wsh1_s= par + 544;
  const float* ws2_s = par + 576;
  const float* wb2_s = par + 608;
  const float* wsh2_s= par + 640;

  // bijective XCD chunking: nwg=625, q=78, r=1
  const int pb = blockIdx.x;
  const int xcd = pb & 7, sub = pb >> 3;
  const int lb = (xcd < 1) ? sub : (79 + (xcd - 1) * 78 + sub);
  const int nbase = lb * 64;

  const int l = tid & 63, wv = tid >> 6;  // wv 0..15
  const int el = l & 15, kg = l >> 4;
  u16* const Rn = &Rx[wv][0];

  __syncthreads();

  const f32x4 z4 = {0.f, 0.f, 0.f, 0.f};

  // ---- software pipeline: idx/et 2 ahead, nb/x frags 1 ahead ----
  int idxv[4], etv[4];
  bf16x8 nb0v[4], nb1v[4];
  union UF { bf16x8 v; uint4 q; } xv[4];

  idxv[0] = nn_idx[(nbase + wv) * 16 + el];
  etv[0]  = etype[(nbase + wv) * 16 + el];
  idxv[1] = nn_idx[(nbase + 16 + wv) * 16 + el];
  etv[1]  = etype[(nbase + 16 + wv) * 16 + el];
  {
    const int nid = nbase + wv;
    const int b = nid / N_, n = nid - b * N_;
    const u16* nbp = nf1b + ((size_t)b * N_ + idxv[0]) * 64 + kg * 8;
    nb0v[0] = *(const bf16x8*)nbp;
    nb1v[0] = *(const bf16x8*)(nbp + 32);
    const float* xp = wfeat + ((size_t)(b * 32 + kg * 8) * N_ + n) * 16 + el;
    float a[8];
#pragma unroll
    for (int j = 0; j < 8; ++j) a[j] = xp[(size_t)j * N_ * 16];
    xv[0].q.x = f2bf2(a[0], a[1]); xv[0].q.y = f2bf2(a[2], a[3]);
    xv[0].q.z = f2bf2(a[4], a[5]); xv[0].q.w = f2bf2(a[6], a[7]);
  }

#pragma unroll
  for (int it = 0; it < 4; ++it) {
    const int nid = nbase + it * 16 + wv;
    const int b = nid / N_;
    const int n = nid - b * N_;
    const int nl = it * 16 + wv;
    const int et = etv[it];

    if (it + 2 < 4) {
      idxv[it + 2] = nn_idx[(nbase + (it + 2) * 16 + wv) * 16 + el];
      etv[it + 2]  = etype[(nbase + (it + 2) * 16 + wv) * 16 + el];
    }
    if (it + 1 < 4) {
      const int nid2 = nbase + (it + 1) * 16 + wv;
      const int b2 = nid2 / N_, n2 = nid2 - b2 * N_;
      const u16* nbp = nf1b + ((size_t)b2 * N_ + idxv[it + 1]) * 64 + kg * 8;
      nb0v[it + 1] = *(const bf16x8*)nbp;
      nb1v[it + 1] = *(const bf16x8*)(nbp + 32);
      const float* xp = wfeat + ((size_t)(b2 * 32 + kg * 8) * N_ + n2) * 16 + el;
      float a[8];
#pragma unroll
      for (int j = 0; j < 8; ++j) a[j] = xp[(size_t)j * N_ * 16];
      xv[it + 1].q.x = f2bf2(a[0], a[1]); xv[it + 1].q.y = f2bf2(a[2], a[3]);
      xv[it + 1].q.z = f2bf2(a[4], a[5]); xv[it + 1].q.w = f2bf2(a[6], a[7]);
    }

    // ---- wf1 = relu(bn(wW1 @ x)) -> R ----
#pragma unroll
    for (int mt = 0; mt < 2; ++mt) {
      bf16x8 a = *(const bf16x8*)&w1_p[(mt * 64 + l) * 8];
      f32x4 wc = __builtin_amdgcn_mfma_f32_16x16x32_bf16(a, xv[it].v, z4, 0, 0, 0);
      int ob = mt * 16 + kg * 4;
      float4 s4 = *(const float4*)&ws1_s[ob];
      float4 b4 = *(const float4*)&wb1_s[ob];
      float4 h4 = *(const float4*)&wsh1_s[ob];
      uint2 d;
      d.x = f2bf2(fmaxf(fmaf(s4.x, wc[0] + b4.x, h4.x), 0.f),
                  fmaxf(fmaf(s4.y, wc[1] + b4.y, h4.y), 0.f));
      d.y = f2bf2(fmaxf(fmaf(s4.z, wc[2] + b4.z, h4.z), 0.f),
                  fmaxf(fmaf(s4.w, wc[3] + b4.w, h4.w), 0.f));
      *(uint2*)&Rn[((mt * 2 + (kg >> 1)) * 16 + el) * 8 + (kg & 1) * 4] = d;
    }
    bf16x8 wff = *(const bf16x8*)&Rn[l * 8];

    // ---- msg: 3 etypes x 4 M-tiles x 2 K-steps, mask folded into B ----
    f32x4 macc[4] = {z4, z4, z4, z4};
    {
      union { bf16x8 v; uint4 q; } nb0u, nb1u;
      nb0u.v = nb0v[it]; nb1u.v = nb1v[it];
#pragma unroll
      for (int t = 0; t < 3; ++t) {
        unsigned msk = (et == t) ? 0xffffffffu : 0u;
        union { bf16x8 v; uint4 q; } b0, b1;
        b0.q.x = nb0u.q.x & msk; b0.q.y = nb0u.q.y & msk;
        b0.q.z = nb0u.q.z & msk; b0.q.w = nb0u.q.w & msk;
        b1.q.x = nb1u.q.x & msk; b1.q.y = nb1u.q.y & msk;
        b1.q.z = nb1u.q.z & msk; b1.q.w = nb1u.q.w & msk;
#pragma unroll
        for (int mt = 0; mt < 4; ++mt) {
          bf16x8 a0 = *(const bf16x8*)&th_p[((t * 8 + mt * 2 + 0) * 64 + l) * 8];
          bf16x8 a1 = *(const bf16x8*)&th_p[((t * 8 + mt * 2 + 1) * 64 + l) * 8];
          macc[mt] = __builtin_amdgcn_mfma_f32_16x16x32_bf16(a0, b0.v, macc[mt], 0, 0, 0);
          macc[mt] = __builtin_amdgcn_mfma_f32_16x16x32_bf16(a1, b1.v, macc[mt], 0, 0, 0);
        }
      }
    }

    // ---- edge conv: edgeW @ [wf1; nb] ----
    f32x4 eacc[2];
#pragma unroll
    for (int mt = 0; mt < 2; ++mt) {
      bf16x8 a0 = *(const bf16x8*)&eW_p[((mt * 3 + 0) * 64 + l) * 8];
      bf16x8 a1 = *(const bf16x8*)&eW_p[((mt * 3 + 1) * 64 + l) * 8];
      bf16x8 a2 = *(const bf16x8*)&eW_p[((mt * 3 + 2) * 64 + l) * 8];
      f32x4 acc = __builtin_amdgcn_mfma_f32_16x16x32_bf16(a0, wff, z4, 0, 0, 0);
      acc = __builtin_amdgcn_mfma_f32_16x16x32_bf16(a1, nb0v[it], acc, 0, 0, 0);
      acc = __builtin_amdgcn_mfma_f32_16x16x32_bf16(a2, nb1v[it], acc, 0, 0, 0);
      eacc[mt] = acc;
    }

    // ---- gate + combine -> p[16] ----
    float p[16];
#pragma unroll
    for (int mt = 0; mt < 4; ++mt) {
      bf16x8 ga = *(const bf16x8*)&gW_p[(mt * 64 + l) * 8];
      f32x4 g = __builtin_amdgcn_mfma_f32_16x16x32_bf16(ga, wff, z4, 0, 0, 0);
      int ob = mt * 16 + kg * 4;
      float4 tb = *(const float4*)&tb_s[et * 64 + ob];
      float4 gb = *(const float4*)&gb_s[ob];
      p[mt * 4 + 0] = (macc[mt][0] + tb.x) * sigm(g[0] + gb.x);
      p[mt * 4 + 1] = (macc[mt][1] + tb.y) * sigm(g[1] + gb.y);
      p[mt * 4 + 2] = (macc[mt][2] + tb.z) * sigm(g[2] + gb.z);
      p[mt * 4 + 3] = (macc[mt][3] + tb.w) * sigm(g[3] + gb.w);
    }

    // ---- reduce-scatter over 16 edges: lane (el,kg) ends with channel
    //      ch = (el>>2)*16 + kg*4 + (el&3) fully summed ----
    {
      const int b0 = el & 1, b1 = (el >> 1) & 1, b2 = (el >> 2) & 1, b3 = (el >> 3) & 1;
      float w8[8];
#pragma unroll
      for (int j = 0; j < 8; ++j) {
        float send = b0 ? p[2 * j] : p[2 * j + 1];
        float keep = b0 ? p[2 * j + 1] : p[2 * j];
        w8[j] = keep + __shfl_xor(send, 1);
      }
      float w4[4];
#pragma unroll
      for (int j = 0; j < 4; ++j) {
        float send = b1 ? w8[2 * j] : w8[2 * j + 1];
        float keep = b1 ? w8[2 * j + 1] : w8[2 * j];
        w4[j] = keep + __shfl_xor(send, 2);
      }
      float w2[2];
#pragma unroll
      for (int j = 0; j < 2; ++j) {
        float send = b2 ? w4[2 * j] : w4[2 * j + 1];
        float keep = b2 ? w4[2 * j + 1] : w4[2 * j];
        w2[j] = keep + __shfl_xor(send, 4);
      }
      float send = b3 ? w2[0] : w2[1];
      float keep = b3 ? w2[1] : w2[0];
      float z = keep + __shfl_xor(send, 8);
      float no = fmaxf(z * 0.0625f, 0.f);
      int ch = ((el >> 2) << 4) + (kg << 2) + (el & 3);
      int su = (ch >> 3) ^ (nl & 7);
      nout_bf[nl * 64 + su * 8 + (ch & 7)] = f2bf(no);
    }

    // ---- w_out = relu(edge + eb) -> R ----
#pragma unroll
    for (int mt = 0; mt < 2; ++mt) {
      int ob = mt * 16 + kg * 4;
      float4 eb4 = *(const float4*)&eb_s[ob];
      uint2 d;
      d.x = f2bf2(fmaxf(eacc[mt][0] + eb4.x, 0.f), fmaxf(eacc[mt][1] + eb4.y, 0.f));
      d.y = f2bf2(fmaxf(eacc[mt][2] + eb4.z, 0.f), fmaxf(eacc[mt][3] + eb4.w, 0.f));
      *(uint2*)&Rn[((mt * 2 + (kg >> 1)) * 16 + el) * 8 + (kg & 1) * 4] = d;
    }
    bf16x8 wof = *(const bf16x8*)&Rn[l * 8];

    // ---- wf2 = relu(bn(wW2 @ w_out)) + wfeat residual, direct store ----
#pragma unroll
    for (int mt = 0; mt < 2; ++mt) {
      bf16x8 a = *(const bf16x8*)&w2_p[(mt * 64 + l) * 8];
      f32x4 fc = __builtin_amdgcn_mfma_f32_16x16x32_bf16(a, wof, z4, 0, 0, 0);
      int ob = mt * 16 + kg * 4;
      float4 s4 = *(const float4*)&ws2_s[ob];
      float4 b4 = *(const float4*)&wb2_s[ob];
      float4 h4 = *(const float4*)&wsh2_s[ob];
      float sv[4] = {s4.x, s4.y, s4.z, s4.w};
      float bv[4] = {b4.x, b4.y, b4.z, b4.w};
      float hv[4] = {h4.x, h4.y, h4.z, h4.w};
#pragma unroll
      for (int r = 0; r < 4; ++r) {
        int a2 = ((b * 32 + ob + r) * N_ + n) * 16 + el;
        float y = fmaxf(fmaf(sv[r], fc[r] + bv[r], hv[r]), 0.f);
        out_wf[a2] = y + wfeat[a2];
      }
    }
  }
  __syncthreads();

  // ---- phase 2: nf2 = relu(bn(nW2 @ n_out)) + node residual, via MFMA ----
  // 16 waves: mt = wv&3 (M-tile), ng = wv>>2 (node group of 16, 0..3).
  {
    const int mt = wv & 3, ng = wv >> 2;
    const int node_l = ng * 16 + el;
    const int nid2 = nbase + node_l;
    const int b2 = nid2 / N_;
    const int n2 = nid2 - b2 * N_;
    const int sw = node_l & 7;
    bf16x8 nb0 = *(const bf16x8*)&nout_bf[node_l * 64 + ((0 + kg) ^ sw) * 8];
    bf16x8 nb1 = *(const bf16x8*)&nout_bf[node_l * 64 + ((4 + kg) ^ sw) * 8];
    bf16x8 a0 = *(const bf16x8*)&nW2f_p[((mt * 2 + 0) * 64 + l) * 8];
    bf16x8 a1 = *(const bf16x8*)&nW2f_p[((mt * 2 + 1) * 64 + l) * 8];
    f32x4 acc = __builtin_amdgcn_mfma_f32_16x16x32_bf16(a0, nb0, z4, 0, 0, 0);
    acc = __builtin_amdgcn_mfma_f32_16x16x32_bf16(a1, nb1, acc, 0, 0, 0);
#pragma unroll
    for (int i = 0; i < 4; ++i) {
      int ch = mt * 16 + kg * 4 + i;
      int off = (b2 * 64 + ch) * N_ + n2;
      float y = fmaxf(fmaf(ns2_s[ch], acc[i] + nb2_s[ch], nsh2_s[ch]), 0.f);
      out_nf[off] = y + node[off];
    }
  }
}

extern "C" void kernel_launch(void* const* d_in, const int* in_sizes, int n_in,
                              void* d_out, int out_size, void* d_ws, size_t ws_size,
                              hipStream_t stream) {
  const float* node    = (const float*)d_in[0];
  const float* wfeat   = (const float*)d_in[1];
  const int*   etype   = (const int*)d_in[2];
  const int*   nn_idx  = (const int*)d_in[3];
  const float* nW1     = (const float*)d_in[4];
  const float* nb1     = (const float*)d_in[5];
  const float* ns1     = (const float*)d_in[6];
  const float* nsh1    = (const float*)d_in[7];
  const float* wW1     = (const float*)d_in[8];
  const float* wb1     = (const float*)d_in[9];
  const float* ws1     = (const float*)d_in[10];
  const float* wsh1    = (const float*)d_in[11];
  const float* theta   = (const float*)d_in[12];
  const float* theta_b = (const float*)d_in[13];
  const float* gateW   = (const float*)d_in[14];
  const float* gate_b  = (const float*)d_in[15];
  const float* edgeW   = (const float*)d_in[16];
  const float* edge_b  = (const float*)d_in[17];
  const float* nW2     = (const float*)d_in[18];
  const float* nb2     = (const float*)d_in[19];
  const float* ns2     = (const float*)d_in[20];
  const float* nsh2    = (const float*)d_in[21];
  const float* wW2     = (const float*)d_in[22];
  const float* wb2     = (const float*)d_in[23];
  const float* ws2     = (const float*)d_in[24];
  const float* wsh2    = (const float*)d_in[25];

  u16*      nf1b = (u16*)d_ws;                                   // 5.12 MB
  unsigned* blob = (unsigned*)((char*)d_ws + 5120000);           // 49.8 KB
  float* out_nf = (float*)d_out;
  float* out_wf = (float*)d_out + (size_t)B_ * 64 * N_;

  k_pack<<<1, 256, 0, stream>>>(theta, edgeW, gateW, wW1, wW2, nW2,
                                theta_b, gate_b, edge_b,
                                ws1, wb1, wsh1, ns2, nb2, nsh2, ws2, wb2, wsh2,
                                blob);
  k_nf1<<<625, 256, 0, stream>>>(node, nW1, nb1, ns1, nsh1, nf1b);
  k_fused<<<625, 1024, 0, stream>>>(node, wfeat, etype, nn_idx, nf1b, blob,
                                    out_nf, out_wf);
}

// Round 9
// 132.787 us; speedup vs baseline: 2.0176x; 2.0176x over previous
//
#include <hip/hip_runtime.h>
#include <hip/hip_bf16.h>
#include <stdint.h>

#define B_ 16
#define N_ 2500

typedef unsigned short u16;
typedef __attribute__((ext_vector_type(8))) short bf16x8;
typedef __attribute__((ext_vector_type(4))) float f32x4;
typedef __attribute__((ext_vector_type(16))) float f32x16;

__device__ __forceinline__ u16 f2bf_sw(float f) {
  unsigned u = __float_as_uint(f);
  return (u16)((u + 0x7fffu + ((u >> 16) & 1u)) >> 16);
}
__device__ __forceinline__ u16 f2bf(float f) {
  __hip_bfloat16 h = __float2bfloat16(f);
  return __builtin_bit_cast(u16, h);
}
__device__ __forceinline__ unsigned f2bf2(float lo, float hi) {
  return (unsigned)f2bf(lo) | ((unsigned)f2bf(hi) << 16);
}
__device__ __forceinline__ float sigm(float x) {
  return __builtin_amdgcn_rcpf(1.f + __expf(-x));
}

// Blob (u32): th 0..6144 (24 frags), eW 6144..7680 (6), gW 7680..8704 (4),
// w1 8704..9216 (2), w2 9216..9728 (2), nW2 9728..11776 (8, 16x16-form),
// params(f32) 11776..12448.
#define BLOB_U32 12448

// ---------- kernel P: pack weights into 32x32-form fragment blob ----------
__global__ __launch_bounds__(256) void k_pack(
    const float* __restrict__ theta, const float* __restrict__ edgeW,
    const float* __restrict__ gateW, const float* __restrict__ wW1,
    const float* __restrict__ wW2, const float* __restrict__ nW2,
    const float* __restrict__ theta_b, const float* __restrict__ gate_b,
    const float* __restrict__ edge_b,
    const float* __restrict__ ws1, const float* __restrict__ wb1, const float* __restrict__ wsh1,
    const float* __restrict__ ns2, const float* __restrict__ nb2, const float* __restrict__ nsh2,
    const float* __restrict__ ws2, const float* __restrict__ wb2, const float* __restrict__ wsh2,
    unsigned* __restrict__ blob) {
  const int tid = threadIdx.x;
  // A-frag 32x32x16: lane (m=l&31, half=l>>5) holds W[Mbase+m][s*16+half*8+j]
  for (int q = tid; q < 6144; q += 256) {  // theta: f = t*8 + mt*4 + s
    int f = q >> 8, lane = (q >> 2) & 63, jp = q & 3;
    int t = f >> 3, mt = (f >> 2) & 1, s = f & 3;
    int m = lane & 31, hf = lane >> 5;
    const float* src = theta + ((size_t)t * 64 + mt * 32 + m) * 64 + s * 16 + hf * 8 + jp * 2;
    blob[q] = (unsigned)f2bf_sw(src[0]) | ((unsigned)f2bf_sw(src[1]) << 16);
  }
  for (int q = tid; q < 1536; q += 256) {  // edgeW: f = s (0..5), M=32 single tile
    int f = q >> 8, lane = (q >> 2) & 63, jp = q & 3;
    int m = lane & 31, hf = lane >> 5;
    const float* src = edgeW + (size_t)m * 96 + f * 16 + hf * 8 + jp * 2;
    blob[6144 + q] = (unsigned)f2bf_sw(src[0]) | ((unsigned)f2bf_sw(src[1]) << 16);
  }
  for (int q = tid; q < 1024; q += 256) {  // gateW: f = mt*2 + s
    int f = q >> 8, lane = (q >> 2) & 63, jp = q & 3;
    int mt = f >> 1, s = f & 1;
    int m = lane & 31, hf = lane >> 5;
    const float* src = gateW + ((size_t)mt * 32 + m) * 32 + s * 16 + hf * 8 + jp * 2;
    blob[7680 + q] = (unsigned)f2bf_sw(src[0]) | ((unsigned)f2bf_sw(src[1]) << 16);
  }
  for (int q = tid; q < 512; q += 256) {  // wW1/wW2: f = s
    int f = q >> 8, lane = (q >> 2) & 63, jp = q & 3;
    int m = lane & 31, hf = lane >> 5;
    const float* s1 = wW1 + (size_t)m * 32 + f * 16 + hf * 8 + jp * 2;
    const float* s2 = wW2 + (size_t)m * 32 + f * 16 + hf * 8 + jp * 2;
    blob[8704 + q] = (unsigned)f2bf_sw(s1[0]) | ((unsigned)f2bf_sw(s1[1]) << 16);
    blob[9216 + q] = (unsigned)f2bf_sw(s2[0]) | ((unsigned)f2bf_sw(s2[1]) << 16);
  }
  for (int q = tid; q < 2048; q += 256) {  // nW2 frags: 16x16 form, f = mt*2 + h
    int f = q >> 8, lane = (q >> 2) & 63, jp = q & 3;
    int mt = f >> 1, h = f & 1;
    int el = lane & 15, kg = lane >> 4;
    const float* s = nW2 + (size_t)(mt * 16 + el) * 64 + h * 32 + kg * 8 + jp * 2;
    blob[9728 + q] = (unsigned)f2bf_sw(s[0]) | ((unsigned)f2bf_sw(s[1]) << 16);
  }
  float* bf = (float*)blob;
  for (int i = tid; i < 672; i += 256) {
    float v;
    if (i < 192)      v = theta_b[i];
    else if (i < 256) v = gate_b[i - 192];
    else if (i < 320) v = ns2[i - 256];
    else if (i < 384) v = nb2[i - 320];
    else if (i < 448) v = nsh2[i - 384];
    else if (i < 480) v = edge_b[i - 448];
    else if (i < 512) v = ws1[i - 480];
    else if (i < 544) v = wb1[i - 512];
    else if (i < 576) v = wsh1[i - 544];
    else if (i < 608) v = ws2[i - 576];
    else if (i < 640) v = wb2[i - 608];
    else              v = wsh2[i - 640];
    bf[11776 + i] = v;
  }
}

// ---------- kernel A: nf1 = relu(bn(nW1 @ node)) -> bf16 [b*N+n][64], MFMA ----------
__global__ __launch_bounds__(256) void k_nf1(
    const float* __restrict__ node, const float* __restrict__ W,
    const float* __restrict__ bia, const float* __restrict__ sc,
    const float* __restrict__ sh, u16* __restrict__ nf1b) {
  __shared__ __align__(16) u16 W_p[8 * 64 * 8];
  __shared__ float bia_s[64], sc_s[64], sh_s[64];
  const int tid = threadIdx.x;
  for (int q = tid; q < 2048; q += 256) {
    int f = q >> 8, lane = (q >> 2) & 63, jp = q & 3;
    int mt = f >> 1, h = f & 1;
    int fel = lane & 15, fkg = lane >> 4;
    const float* src = W + (size_t)(mt * 16 + fel) * 64 + h * 32 + fkg * 8 + jp * 2;
    ((unsigned*)W_p)[q] = f2bf2(src[0], src[1]);
  }
  if (tid < 64) { bia_s[tid] = bia[tid]; sc_s[tid] = sc[tid]; sh_s[tid] = sh[tid]; }
  __syncthreads();

  const int l = tid & 63, wv = tid >> 6;
  const int el = l & 15, kg = l >> 4;
  const int bn = blockIdx.x * 64 + wv * 16 + el;
  const int b = bn / N_;
  const int n = bn - b * N_;

  union UF { bf16x8 v; uint4 q; } xb0, xb1;
  const float* xp0 = node + (size_t)(b * 64 + kg * 8) * N_ + n;
  const float* xp1 = node + (size_t)(b * 64 + 32 + kg * 8) * N_ + n;
  {
    float a0[8], a1[8];
#pragma unroll
    for (int j = 0; j < 8; ++j) { a0[j] = xp0[(size_t)j * N_]; a1[j] = xp1[(size_t)j * N_]; }
    xb0.q.x = f2bf2(a0[0], a0[1]); xb0.q.y = f2bf2(a0[2], a0[3]);
    xb0.q.z = f2bf2(a0[4], a0[5]); xb0.q.w = f2bf2(a0[6], a0[7]);
    xb1.q.x = f2bf2(a1[0], a1[1]); xb1.q.y = f2bf2(a1[2], a1[3]);
    xb1.q.z = f2bf2(a1[4], a1[5]); xb1.q.w = f2bf2(a1[6], a1[7]);
  }
  const f32x4 z4 = {0.f, 0.f, 0.f, 0.f};
#pragma unroll
  for (int mt = 0; mt < 4; ++mt) {
    bf16x8 a0 = *(const bf16x8*)&W_p[((mt * 2 + 0) * 64 + l) * 8];
    bf16x8 a1 = *(const bf16x8*)&W_p[((mt * 2 + 1) * 64 + l) * 8];
    f32x4 acc = __builtin_amdgcn_mfma_f32_16x16x32_bf16(a0, xb0.v, z4, 0, 0, 0);
    acc = __builtin_amdgcn_mfma_f32_16x16x32_bf16(a1, xb1.v, acc, 0, 0, 0);
    int ob = mt * 16 + kg * 4;
    float4 s4 = *(const float4*)&sc_s[ob];
    float4 b4 = *(const float4*)&bia_s[ob];
    float4 h4 = *(const float4*)&sh_s[ob];
    uint2 d;
    d.x = f2bf2(fmaxf(fmaf(s4.x, acc[0] + b4.x, h4.x), 0.f),
                fmaxf(fmaf(s4.y, acc[1] + b4.y, h4.y), 0.f));
    d.y = f2bf2(fmaxf(fmaf(s4.z, acc[2] + b4.z, h4.z), 0.f),
                fmaxf(fmaf(s4.w, acc[3] + b4.w, h4.w), 0.f));
    *(uint2*)&nf1b[(size_t)bn * 64 + ob] = d;
  }
}

// ---------- kernel B: fused pair-form (32x32x16) message passing ----------
// 512 threads = 8 waves; 32-node window (16 pairs); wave wv: pairs wv, wv+8.
__global__ __launch_bounds__(512, 2) void k_fused(
    const float* __restrict__ node, const float* __restrict__ wfeat,
    const int* __restrict__ etype, const int* __restrict__ nn_idx,
    const u16* __restrict__ nf1b, const unsigned* __restrict__ blob,
    float* __restrict__ out_nf, float* __restrict__ out_wf) {

  __shared__ __align__(16) unsigned char sm[BLOB_U32 * 4];  // 49792 B
  __shared__ __align__(16) u16 nout_bf[32 * 64];            // 4096 B
  __shared__ __align__(16) u16 Rx[8][1024];                 // 16384 B (2 frag regions/wave)

  const int tid = threadIdx.x;
  for (int i = tid; i < BLOB_U32 / 4; i += 512)
    ((uint4*)sm)[i] = ((const uint4*)blob)[i];

  const u16* th_p   = (const u16*)sm;
  const u16* eW_p   = (const u16*)(sm + 24576);
  const u16* gW_p   = (const u16*)(sm + 30720);
  const u16* w1_p   = (const u16*)(sm + 34816);
  const u16* w2_p   = (const u16*)(sm + 36864);
  const u16* nW2f_p = (const u16*)(sm + 38912);
  const float* par = (const float*)(sm + 47104);
  const float* tb_s  = par;
  const float* gb_s  = par + 192;
  const float* ns2_s = par + 256;
  const float* nb2_s = par + 320;
  const float* nsh2_s= par + 384;
  const float* eb_s  = par + 448;
  const float* ws1_s = par + 480;
  const float* wb1_s = par + 512;
  const float* wsh1_s= par + 544;
  const float* ws2_s = par + 576;
  const float* wb2_s = par + 608;
  const float* wsh2_s= par + 640;

  // bijective XCD chunking: nwg=1250, q=156, r=2
  const int pb = blockIdx.x;
  const int xcd = pb & 7, sub = pb >> 3;
  const int lb = (xcd < 2) ? (xcd * 157 + sub) : (2 * 157 + (xcd - 2) * 156 + sub);
  const int nbase = lb * 32;

  const int l = tid & 63, wv = tid >> 6;
  const int col = l & 31, half = l >> 5;
  const int en = col & 15, nd = col >> 4;
  u16* const Rw = &Rx[wv][0];

  __syncthreads();

  const f32x16 z16 = {0.f,0.f,0.f,0.f,0.f,0.f,0.f,0.f,0.f,0.f,0.f,0.f,0.f,0.f,0.f,0.f};

  // per-iteration staged data (arrays indexed by unrolled it -> static)
  int idxv[2], etv[2];
  bf16x8 nbf[2][4];
  bf16x8 xf[2][2];

  idxv[0] = nn_idx[(nbase + 2 * wv + nd) * 16 + en];
  etv[0]  = etype[(nbase + 2 * wv + nd) * 16 + en];
  idxv[1] = nn_idx[(nbase + 16 + 2 * wv + nd) * 16 + en];
  etv[1]  = etype[(nbase + 16 + 2 * wv + nd) * 16 + en];
  {
    const int nid = nbase + 2 * wv + nd;
    const int b = nid / N_, n = nid - b * N_;
    const u16* nbp = nf1b + ((size_t)b * N_ + idxv[0]) * 64 + half * 8;
#pragma unroll
    for (int s = 0; s < 4; ++s) nbf[0][s] = *(const bf16x8*)(nbp + s * 16);
    const float* xpp = wfeat + ((size_t)(b * 32 + half * 8) * N_ + n) * 16 + en;
#pragma unroll
    for (int s = 0; s < 2; ++s) {
      float a[8];
#pragma unroll
      for (int j = 0; j < 8; ++j) a[j] = xpp[(size_t)(s * 16 + j) * N_ * 16];
      union { bf16x8 v; uint4 q; } u;
      u.q.x = f2bf2(a[0], a[1]); u.q.y = f2bf2(a[2], a[3]);
      u.q.z = f2bf2(a[4], a[5]); u.q.w = f2bf2(a[6], a[7]);
      xf[0][s] = u.v;
    }
  }

#pragma unroll
  for (int it = 0; it < 2; ++it) {
    const int nid = nbase + it * 16 + 2 * wv + nd;
    const int b = nid / N_;
    const int n = nid - b * N_;
    const int nl = it * 16 + 2 * wv + nd;  // node-local 0..31
    const int et = etv[it];

    if (it == 0) {  // prefetch iteration 1
      const int nid2 = nbase + 16 + 2 * wv + nd;
      const int b2 = nid2 / N_, n2 = nid2 - b2 * N_;
      const u16* nbp = nf1b + ((size_t)b2 * N_ + idxv[1]) * 64 + half * 8;
#pragma unroll
      for (int s = 0; s < 4; ++s) nbf[1][s] = *(const bf16x8*)(nbp + s * 16);
      const float* xpp = wfeat + ((size_t)(b2 * 32 + half * 8) * N_ + n2) * 16 + en;
#pragma unroll
      for (int s = 0; s < 2; ++s) {
        float a[8];
#pragma unroll
        for (int j = 0; j < 8; ++j) a[j] = xpp[(size_t)(s * 16 + j) * N_ * 16];
        union { bf16x8 v; uint4 q; } u;
        u.q.x = f2bf2(a[0], a[1]); u.q.y = f2bf2(a[2], a[3]);
        u.q.z = f2bf2(a[4], a[5]); u.q.w = f2bf2(a[6], a[7]);
        xf[1][s] = u.v;
      }
    }

    // ---- wf1 = relu(bn(wW1 @ x)) : 2 MFMAs (32 ch x 32 cols) ----
    f32x16 wc;
    {
      bf16x8 a0 = *(const bf16x8*)&w1_p[(0 * 64 + l) * 8];
      bf16x8 a1 = *(const bf16x8*)&w1_p[(1 * 64 + l) * 8];
      wc = __builtin_amdgcn_mfma_f32_32x32x16_bf16(a0, xf[it][0], z16, 0, 0, 0);
      wc = __builtin_amdgcn_mfma_f32_32x32x16_bf16(a1, xf[it][1], wc, 0, 0, 0);
    }
    // epilogue + frag-major transpose write: quad q covers ch q*8+4*half..+3
#pragma unroll
    for (int q = 0; q < 4; ++q) {
      int chb = q * 8 + 4 * half;
      float4 s4 = *(const float4*)&ws1_s[chb];
      float4 b4 = *(const float4*)&wb1_s[chb];
      float4 h4 = *(const float4*)&wsh1_s[chb];
      float y0 = fmaxf(fmaf(s4.x, wc[q * 4 + 0] + b4.x, h4.x), 0.f);
      float y1 = fmaxf(fmaf(s4.y, wc[q * 4 + 1] + b4.y, h4.y), 0.f);
      float y2 = fmaxf(fmaf(s4.z, wc[q * 4 + 2] + b4.z, h4.z), 0.f);
      float y3 = fmaxf(fmaf(s4.w, wc[q * 4 + 3] + b4.w, h4.w), 0.f);
      uint2 d; d.x = f2bf2(y0, y1); d.y = f2bf2(y2, y3);
      int Q = 2 * q + half;
      *(uint2*)&Rw[(Q >> 2) * 512 + (col + 32 * ((Q >> 1) & 1)) * 8 + (Q & 1) * 4] = d;
    }
    bf16x8 wff0 = *(const bf16x8*)&Rw[l * 8];
    bf16x8 wff1 = *(const bf16x8*)&Rw[512 + l * 8];

    // ---- edge conv: eacc = edgeW @ [wf1; nb] : 6 MFMAs ----
    f32x16 eacc;
    {
      bf16x8 e0 = *(const bf16x8*)&eW_p[(0 * 64 + l) * 8];
      bf16x8 e1 = *(const bf16x8*)&eW_p[(1 * 64 + l) * 8];
      bf16x8 e2 = *(const bf16x8*)&eW_p[(2 * 64 + l) * 8];
      bf16x8 e3 = *(const bf16x8*)&eW_p[(3 * 64 + l) * 8];
      bf16x8 e4 = *(const bf16x8*)&eW_p[(4 * 64 + l) * 8];
      bf16x8 e5 = *(const bf16x8*)&eW_p[(5 * 64 + l) * 8];
      eacc = __builtin_amdgcn_mfma_f32_32x32x16_bf16(e0, wff0, z16, 0, 0, 0);
      eacc = __builtin_amdgcn_mfma_f32_32x32x16_bf16(e1, wff1, eacc, 0, 0, 0);
      eacc = __builtin_amdgcn_mfma_f32_32x32x16_bf16(e2, nbf[it][0], eacc, 0, 0, 0);
      eacc = __builtin_amdgcn_mfma_f32_32x32x16_bf16(e3, nbf[it][1], eacc, 0, 0, 0);
      eacc = __builtin_amdgcn_mfma_f32_32x32x16_bf16(e4, nbf[it][2], eacc, 0, 0, 0);
      eacc = __builtin_amdgcn_mfma_f32_32x32x16_bf16(e5, nbf[it][3], eacc, 0, 0, 0);
    }
    // w_out = relu(eacc + eb) -> frag-major R (overwrites wf1; wff held in regs)
#pragma unroll
    for (int q = 0; q < 4; ++q) {
      int chb = q * 8 + 4 * half;
      float4 eb4 = *(const float4*)&eb_s[chb];
      float y0 = fmaxf(eacc[q * 4 + 0] + eb4.x, 0.f);
      float y1 = fmaxf(eacc[q * 4 + 1] + eb4.y, 0.f);
      float y2 = fmaxf(eacc[q * 4 + 2] + eb4.z, 0.f);
      float y3 = fmaxf(eacc[q * 4 + 3] + eb4.w, 0.f);
      uint2 d; d.x = f2bf2(y0, y1); d.y = f2bf2(y2, y3);
      int Q = 2 * q + half;
      *(uint2*)&Rw[(Q >> 2) * 512 + (col + 32 * ((Q >> 1) & 1)) * 8 + (Q & 1) * 4] = d;
    }
    bf16x8 wof0 = *(const bf16x8*)&Rw[l * 8];
    bf16x8 wof1 = *(const bf16x8*)&Rw[512 + l * 8];

    // ---- msg: 3 etypes x 2 M-tiles x 4 K-steps = 24 MFMAs, mask in B ----
    f32x16 macc0 = z16, macc1 = z16;
#pragma unroll
    for (int t = 0; t < 3; ++t) {
      unsigned msk = (et == t) ? 0xffffffffu : 0u;
      bf16x8 bm[4];
#pragma unroll
      for (int s = 0; s < 4; ++s) {
        union { bf16x8 v; uint4 q; } u;
        u.v = nbf[it][s];
        u.q.x &= msk; u.q.y &= msk; u.q.z &= msk; u.q.w &= msk;
        bm[s] = u.v;
      }
#pragma unroll
      for (int s = 0; s < 4; ++s) {
        bf16x8 a0 = *(const bf16x8*)&th_p[((t * 8 + 0 * 4 + s) * 64 + l) * 8];
        bf16x8 a1 = *(const bf16x8*)&th_p[((t * 8 + 1 * 4 + s) * 64 + l) * 8];
        macc0 = __builtin_amdgcn_mfma_f32_32x32x16_bf16(a0, bm[s], macc0, 0, 0, 0);
        macc1 = __builtin_amdgcn_mfma_f32_32x32x16_bf16(a1, bm[s], macc1, 0, 0, 0);
      }
    }

    // ---- gate (per M-tile) + combine -> p[32] ----
    float p[32];
#pragma unroll
    for (int mt = 0; mt < 2; ++mt) {
      bf16x8 g0 = *(const bf16x8*)&gW_p[((mt * 2 + 0) * 64 + l) * 8];
      bf16x8 g1 = *(const bf16x8*)&gW_p[((mt * 2 + 1) * 64 + l) * 8];
      f32x16 gacc = __builtin_amdgcn_mfma_f32_32x32x16_bf16(g0, wff0, z16, 0, 0, 0);
      gacc = __builtin_amdgcn_mfma_f32_32x32x16_bf16(g1, wff1, gacc, 0, 0, 0);
#pragma unroll
      for (int q = 0; q < 4; ++q) {
        int chb = mt * 32 + q * 8 + 4 * half;
        float4 tb4 = *(const float4*)&tb_s[et * 64 + chb];
        float4 gb4 = *(const float4*)&gb_s[chb];
        float mv0 = (mt ? macc1[q * 4 + 0] : macc0[q * 4 + 0]) + tb4.x;
        float mv1 = (mt ? macc1[q * 4 + 1] : macc0[q * 4 + 1]) + tb4.y;
        float mv2 = (mt ? macc1[q * 4 + 2] : macc0[q * 4 + 2]) + tb4.z;
        float mv3 = (mt ? macc1[q * 4 + 3] : macc0[q * 4 + 3]) + tb4.w;
        p[mt * 16 + q * 4 + 0] = mv0 * sigm(gacc[q * 4 + 0] + gb4.x);
        p[mt * 16 + q * 4 + 1] = mv1 * sigm(gacc[q * 4 + 1] + gb4.y);
        p[mt * 16 + q * 4 + 2] = mv2 * sigm(gacc[q * 4 + 2] + gb4.z);
        p[mt * 16 + q * 4 + 3] = mv3 * sigm(gacc[q * 4 + 3] + gb4.w);
      }
    }

    // ---- reduce-scatter over 16 edge-columns (within node group) ----
    {
      const int b0 = en & 1, b1 = (en >> 1) & 1, b2 = (en >> 2) & 1, b3 = (en >> 3) & 1;
      float r16[16];
#pragma unroll
      for (int j = 0; j < 16; ++j) {
        float send = b0 ? p[2 * j] : p[2 * j + 1];
        float keep = b0 ? p[2 * j + 1] : p[2 * j];
        r16[j] = keep + __shfl_xor(send, 1);
      }
      float r8[8];
#pragma unroll
      for (int j = 0; j < 8; ++j) {
        float send = b1 ? r16[2 * j] : r16[2 * j + 1];
        float keep = b1 ? r16[2 * j + 1] : r16[2 * j];
        r8[j] = keep + __shfl_xor(send, 2);
      }
      float r4[4];
#pragma unroll
      for (int j = 0; j < 4; ++j) {
        float send = b2 ? r8[2 * j] : r8[2 * j + 1];
        float keep = b2 ? r8[2 * j + 1] : r8[2 * j];
        r4[j] = keep + __shfl_xor(send, 4);
      }
      float r2[2];
#pragma unroll
      for (int j = 0; j < 2; ++j) {
        float send = b3 ? r4[2 * j] : r4[2 * j + 1];
        float keep = b3 ? r4[2 * j + 1] : r4[2 * j];
        r2[j] = keep + __shfl_xor(send, 8);
      }
      // survivors: m = en (mt=0) and m = en+16 (mt=1); ch = mt*32 + chof(en,half)
      int ch0 = (en & 3) + 8 * ((en >> 2) & 3) + 4 * half;
      float v0 = fmaxf(r2[0] * 0.0625f, 0.f);
      float v1 = fmaxf(r2[1] * 0.0625f, 0.f);
      nout_bf[nl * 64 + (((ch0 >> 3) ^ (nl & 7)) << 3) + (ch0 & 7)] = f2bf(v0);
      int ch1 = ch0 + 32;
      nout_bf[nl * 64 + (((ch1 >> 3) ^ (nl & 7)) << 3) + (ch1 & 7)] = f2bf(v1);
    }

    // ---- wf2 = relu(bn(wW2 @ w_out)) + wfeat residual : 2 MFMAs ----
    {
      bf16x8 a0 = *(const bf16x8*)&w2_p[(0 * 64 + l) * 8];
      bf16x8 a1 = *(const bf16x8*)&w2_p[(1 * 64 + l) * 8];
      f32x16 fc = __builtin_amdgcn_mfma_f32_32x32x16_bf16(a0, wof0, z16, 0, 0, 0);
      fc = __builtin_amdgcn_mfma_f32_32x32x16_bf16(a1, wof1, fc, 0, 0, 0);
#pragma unroll
      for (int q = 0; q < 4; ++q) {
        int chb = q * 8 + 4 * half;
        float4 s4 = *(const float4*)&ws2_s[chb];
        float4 b4 = *(const float4*)&wb2_s[chb];
        float4 h4 = *(const float4*)&wsh2_s[chb];
        float sv[4] = {s4.x, s4.y, s4.z, s4.w};
        float bv[4] = {b4.x, b4.y, b4.z, b4.w};
        float hv[4] = {h4.x, h4.y, h4.z, h4.w};
#pragma unroll
        for (int i = 0; i < 4; ++i) {
          int ch = chb + i;
          size_t a2 = (((size_t)b * 32 + ch) * N_ + n) * 16 + en;
          float y = fmaxf(fmaf(sv[i], fc[q * 4 + i] + bv[i], hv[i]), 0.f);
          out_wf[a2] = y + wfeat[a2];
        }
      }
    }
  }
  __syncthreads();

  // ---- phase 2: nf2 = relu(bn(nW2 @ n_out)) + node residual (16x16 MFMA) ----
  {
    const int el = l & 15, kg = l >> 4;
    const int mt = wv & 3, ng = wv >> 2;
    const int node_l = ng * 16 + el;
    const int nid2 = nbase + node_l;
    const int b2 = nid2 / N_;
    const int n2 = nid2 - b2 * N_;
    const int sw = node_l & 7;
    const f32x4 z4 = {0.f, 0.f, 0.f, 0.f};
    bf16x8 nb0 = *(const bf16x8*)&nout_bf[node_l * 64 + ((0 + kg) ^ sw) * 8];
    bf16x8 nb1 = *(const bf16x8*)&nout_bf[node_l * 64 + ((4 + kg) ^ sw) * 8];
    bf16x8 a0 = *(const bf16x8*)&nW2f_p[((mt * 2 + 0) * 64 + l) * 8];
    bf16x8 a1 = *(const bf16x8*)&nW2f_p[((mt * 2 + 1) * 64 + l) * 8];
    f32x4 acc = __builtin_amdgcn_mfma_f32_16x16x32_bf16(a0, nb0, z4, 0, 0, 0);
    acc = __builtin_amdgcn_mfma_f32_16x16x32_bf16(a1, nb1, acc, 0, 0, 0);
#pragma unroll
    for (int i = 0; i < 4; ++i) {
      int ch = mt * 16 + kg * 4 + i;
      size_t off = ((size_t)b2 * 64 + ch) * N_ + n2;
      float y = fmaxf(fmaf(ns2_s[ch], acc[i] + nb2_s[ch], nsh2_s[ch]), 0.f);
      out_nf[off] = y + node[off];
    }
  }
}

extern "C" void kernel_launch(void* const* d_in, const int* in_sizes, int n_in,
                              void* d_out, int out_size, void* d_ws, size_t ws_size,
                              hipStream_t stream) {
  const float* node    = (const float*)d_in[0];
  const float* wfeat   = (const float*)d_in[1];
  const int*   etype   = (const int*)d_in[2];
  const int*   nn_idx  = (const int*)d_in[3];
  const float* nW1     = (const float*)d_in[4];
  const float* nb1     = (const float*)d_in[5];
  const float* ns1     = (const float*)d_in[6];
  const float* nsh1    = (const float*)d_in[7];
  const float* wW1     = (const float*)d_in[8];
  const float* wb1     = (const float*)d_in[9];
  const float* ws1     = (const float*)d_in[10];
  const float* wsh1    = (const float*)d_in[11];
  const float* theta   = (const float*)d_in[12];
  const float* theta_b = (const float*)d_in[13];
  const float* gateW   = (const float*)d_in[14];
  const float* gate_b  = (const float*)d_in[15];
  const float* edgeW   = (const float*)d_in[16];
  const float* edge_b  = (const float*)d_in[17];
  const float* nW2     = (const float*)d_in[18];
  const float* nb2     = (const float*)d_in[19];
  const float* ns2     = (const float*)d_in[20];
  const float* nsh2    = (const float*)d_in[21];
  const float* wW2     = (const float*)d_in[22];
  const float* wb2     = (const float*)d_in[23];
  const float* ws2     = (const float*)d_in[24];
  const float* wsh2    = (const float*)d_in[25];

  u16*      nf1b = (u16*)d_ws;                                   // 5.12 MB
  unsigned* blob = (unsigned*)((char*)d_ws + 5120000);           // 49.8 KB
  float* out_nf = (float*)d_out;
  float* out_wf = (float*)d_out + (size_t)B_ * 64 * N_;

  k_pack<<<1, 256, 0, stream>>>(theta, edgeW, gateW, wW1, wW2, nW2,
                                theta_b, gate_b, edge_b,
                                ws1, wb1, wsh1, ns2, nb2, nsh2, ws2, wb2, wsh2,
                                blob);
  k_nf1<<<625, 256, 0, stream>>>(node, nW1, nb1, ns1, nsh1, nf1b);
  k_fused<<<1250, 512, 0, stream>>>(node, wfeat, etype, nn_idx, nf1b, blob,
                                    out_nf, out_wf);
}